// Round 1
// baseline (2213.414 us; speedup 1.0000x reference)
//
#include <hip/hip_runtime.h>

#define S 1024
#define Bb 4
#define Hh 16
#define DHh 64
#define Dm 1024
#define DIi 4096
#define Vv 16000
#define Lll 4

typedef __attribute__((ext_vector_type(4))) float f32x4;
typedef __attribute__((ext_vector_type(8))) __bf16 bf16x8;
typedef __attribute__((ext_vector_type(8))) unsigned short u16x8;
typedef __attribute__((ext_vector_type(4))) unsigned short u16x4;

__device__ __forceinline__ unsigned short f2bf(float f) {
  unsigned int u = __float_as_uint(f);
  u += 0x7fffu + ((u >> 16) & 1u);
  return (unsigned short)(u >> 16);
}

__device__ __forceinline__ void gload_lds16(const void* g, void* l) {
  __builtin_amdgcn_global_load_lds((const __attribute__((address_space(1))) unsigned int*)g,
                                   (__attribute__((address_space(3))) unsigned int*)l, 16, 0, 0);
}

__device__ __forceinline__ f32x4 mfma_bf16(bf16x8 a, bf16x8 b, f32x4 c) {
  return __builtin_amdgcn_mfma_f32_16x16x32_bf16(a, b, c, 0, 0, 0);
}

// ---------------- embedding ----------------
__global__ __launch_bounds__(256) void embed_k(const int* __restrict__ tokens,
                                               const float* __restrict__ we,
                                               float* __restrict__ h) {
  int row = blockIdx.x;                 // s*B+b
  int t = threadIdx.x;
  int tok = tokens[row];
  f32x4 v = *(const f32x4*)&we[(long)tok * Dm + t * 4];
  *(f32x4*)&h[(long)row * Dm + t * 4] = v;
}

// ---------------- sinusoidal r matrix (bf16) ----------------
__global__ __launch_bounds__(256) void posr_k(unsigned short* __restrict__ r) {
  int idx = blockIdx.x * 256 + threadIdx.x;   // S*Dm
  int u = idx >> 10, d = idx & 1023;
  float pos = (float)(S - 1 - u);
  int j = d & 511;
  float invf = powf(10000.0f, -(float)j * (1.0f / 512.0f));
  float a = pos * invf;
  r[idx] = f2bf(d < 512 ? sinf(a) : cosf(a));
}

// ---------------- weight convert+transpose: W[K,N] f32 -> WT[N,K] bf16 ----------------
__global__ __launch_bounds__(256) void wcvt_t(const float* __restrict__ W,
                                              unsigned short* __restrict__ WT,
                                              int Kd, int Nd) {
  __shared__ unsigned short tile[32][40];
  int n0 = blockIdx.x * 32, k0 = blockIdx.y * 32;
  const float* Wb = W + (long)blockIdx.z * Kd * Nd;
  unsigned short* WTb = WT + (long)blockIdx.z * Kd * Nd;
  int t = threadIdx.x;
  int rr = t >> 3, c4 = (t & 7) * 4;
  f32x4 v = *(const f32x4*)&Wb[(long)(k0 + rr) * Nd + n0 + c4];
#pragma unroll
  for (int e = 0; e < 4; ++e) tile[rr][c4 + e] = f2bf(v[e]);
  __syncthreads();
  if (t < 128) {
    int n = t >> 2, k8 = (t & 3) * 8;
    u16x8 pk;
#pragma unroll
    for (int e = 0; e < 8; ++e) pk[e] = tile[k8 + e][n];
    *(u16x8*)&WTb[(long)(n0 + n) * Kd + k0 + k8] = pk;
  }
}

// ---------------- GEMM: C[M,N] = A[M,K](bf16) * BT[N,K]^T (bf16) + bias[N], f32 out ----------------
__global__ __launch_bounds__(256) void gemm_bt(const unsigned short* __restrict__ A,
                                               const unsigned short* __restrict__ BT,
                                               const float* __restrict__ bias,
                                               float* __restrict__ C,
                                               int M, int N, int K) {
  __shared__ unsigned short As[128 * 32];
  __shared__ unsigned short Bs[128 * 32];
  const int tid = threadIdx.x;
  const int lane = tid & 63;
  const int w = tid >> 6;
  const int bm = blockIdx.y * 128, bn = blockIdx.x * 128;
  const int wr = (w >> 1) * 64, wc = (w & 1) * 64;
  f32x4 acc[4][4] = {};

  const int rrow = tid >> 2;
  const int rcol = (tid & 3) * 8;
  const unsigned short* a0 = A + (long)(bm + rrow) * K + rcol;
  const unsigned short* a1 = A + (long)(bm + rrow + 64) * K + rcol;
  const unsigned short* b0 = BT + (long)(bn + rrow) * K + rcol;
  const unsigned short* b1 = BT + (long)(bn + rrow + 64) * K + rcol;
  unsigned short* lA0 = &As[w * 512];
  unsigned short* lA1 = &As[2048 + w * 512];
  unsigned short* lB0 = &Bs[w * 512];
  unsigned short* lB1 = &Bs[2048 + w * 512];
  const int la = lane & 15, lk = (lane >> 4) * 8;

  for (int k0 = 0; k0 < K; k0 += 32) {
    __syncthreads();
    gload_lds16(a0 + k0, lA0);
    gload_lds16(a1 + k0, lA1);
    gload_lds16(b0 + k0, lB0);
    gload_lds16(b1 + k0, lB1);
    __syncthreads();
    bf16x8 af[4], bq[4];
#pragma unroll
    for (int mi = 0; mi < 4; ++mi) af[mi] = *(const bf16x8*)&As[(wr + mi * 16 + la) * 32 + lk];
#pragma unroll
    for (int ni = 0; ni < 4; ++ni) bq[ni] = *(const bf16x8*)&Bs[(wc + ni * 16 + la) * 32 + lk];
#pragma unroll
    for (int mi = 0; mi < 4; ++mi)
#pragma unroll
      for (int ni = 0; ni < 4; ++ni)
        acc[mi][ni] = mfma_bf16(af[mi], bq[ni], acc[mi][ni]);
  }
  const int cr = (lane >> 4) * 4;
#pragma unroll
  for (int mi = 0; mi < 4; ++mi) {
#pragma unroll
    for (int ni = 0; ni < 4; ++ni) {
      int col = bn + wc + ni * 16 + la;
      float bv = bias[col];
      int row = bm + wr + mi * 16 + cr;
#pragma unroll
      for (int e = 0; e < 4; ++e)
        C[(long)(row + e) * N + col] = acc[mi][ni][e] + bv;
    }
  }
}

// ---------------- qkv post: split + add biases, bf16, [B,H,S,DH] layouts ----------------
__global__ __launch_bounds__(256) void qkv_prep(const float* __restrict__ q3,
                                                const float* __restrict__ rwb,
                                                const float* __restrict__ rrb,
                                                unsigned short* __restrict__ qw,
                                                unsigned short* __restrict__ qr,
                                                unsigned short* __restrict__ kbuf) {
  int idx = blockIdx.x * 256 + threadIdx.x;   // S*B*1024
  int col = idx & 1023;
  int row = idx >> 10;                        // s*B+b
  int s = row >> 2, b = row & 3;
  int n = col >> 6, d = col & 63;
  float qv = q3[(long)row * 3072 + col];
  float kv = q3[(long)row * 3072 + 1024 + col];
  long o = ((long)(b * Hh + n) * S + s) * 64 + d;
  qw[o] = f2bf(qv + rwb[col]);
  qr[o] = f2bf(qv + rrb[col]);
  kbuf[o] = f2bf(kv);
}

// ---------------- v transpose: [S,B,(2048+col)] f32 -> vT[B*H, DH, S] bf16 ----------------
__global__ __launch_bounds__(256) void vt_prep(const float* __restrict__ q3,
                                               unsigned short* __restrict__ vT) {
  __shared__ unsigned short tile[64][72];
  const int it = blockIdx.x, bn = blockIdx.y;
  const int nh = bn & 15, bbv = bn >> 4;
  const int t = threadIdx.x;
  const int i = t >> 2, c16 = (t & 3) * 16;
  const float* src = q3 + ((long)(it * 64 + i) * Bb + bbv) * 3072 + 2048 + nh * 64 + c16;
#pragma unroll
  for (int e = 0; e < 16; e += 4) {
    f32x4 v = *(const f32x4*)(src + e);
#pragma unroll
    for (int x = 0; x < 4; ++x) tile[i][c16 + e + x] = f2bf(v[x]);
  }
  __syncthreads();
  for (int cc = t; cc < 512; cc += 256) {
    int d = cc >> 3, i8 = (cc & 7) * 8;
    u16x8 pk;
#pragma unroll
    for (int e = 0; e < 8; ++e) pk[e] = tile[i8 + e][d];
    *(u16x8*)&vT[((long)bn * 64 + d) * S + it * 64 + i8] = pk;
  }
}

// ---------------- rk reorder: rkall[S, L*1024] f32 -> rkb[L,H,S,DH] bf16 ----------------
__global__ __launch_bounds__(256) void rkb_prep(const float* __restrict__ rkall,
                                                unsigned short* __restrict__ rkb) {
  int idx = blockIdx.x * 256 + threadIdx.x;   // L*H*S*64
  int d = idx & 63, u = (idx >> 6) & 1023, nl = idx >> 16;
  int l = nl >> 4, n = nl & 15;
  rkb[idx] = f2bf(rkall[(long)u * 4096 + l * 1024 + n * 64 + d]);
}

// ---------------- fused rel-attention (flash, per 16 q-rows per wave) ----------------
__global__ __launch_bounds__(256) void attn_k(const unsigned short* __restrict__ qw,
                                              const unsigned short* __restrict__ qr,
                                              const unsigned short* __restrict__ kbuf,
                                              const unsigned short* __restrict__ vT,
                                              const unsigned short* __restrict__ rk,
                                              unsigned short* __restrict__ vec) {
  __shared__ unsigned short plds[4][16][72];
  const int tid = threadIdx.x, lane = tid & 63, w = tid >> 6;
  const int itile = blockIdx.x & 15;
  const int bn = blockIdx.x >> 4;
  const int nh = bn & 15, bbv = bn >> 4;
  const int iw = itile * 64 + w * 16;
  const int la = lane & 15, lk = (lane >> 4) * 8;

  bf16x8 qwf[2], qrf[2];
  {
    const unsigned short* qp = qw + ((long)bn * S + iw + la) * 64 + lk;
    qwf[0] = *(const bf16x8*)qp;
    qwf[1] = *(const bf16x8*)(qp + 32);
    const unsigned short* qp2 = qr + ((long)bn * S + iw + la) * 64 + lk;
    qrf[0] = *(const bf16x8*)qp2;
    qrf[1] = *(const bf16x8*)(qp2 + 32);
  }
  f32x4 opv[4] = {};
  float m_[4] = {-3e38f, -3e38f, -3e38f, -3e38f};
  float l_[4] = {0.f, 0.f, 0.f, 0.f};
  const int ntiles = (iw + 15) / 64 + 1;
  for (int jt = 0; jt < ntiles; ++jt) {
    const int j0 = jt * 64;
    f32x4 ac[4] = {};
    f32x4 gg[5] = {};
#pragma unroll
    for (int f = 0; f < 4; ++f) {
      const unsigned short* kp = kbuf + ((long)bn * S + j0 + f * 16 + la) * 64 + lk;
      ac[f] = mfma_bf16(qwf[0], *(const bf16x8*)kp, ac[f]);
      ac[f] = mfma_bf16(qwf[1], *(const bf16x8*)(kp + 32), ac[f]);
    }
    const int u0 = S - 16 - iw + j0;
#pragma unroll
    for (int g = 0; g < 5; ++g) {
      int u = u0 + g * 16 + la;
      u = (u > S - 1) ? (S - 1) : u;
      const unsigned short* rp = rk + ((long)nh * S + u) * 64 + lk;
      gg[g] = mfma_bf16(qrf[0], *(const bf16x8*)rp, gg[g]);
      gg[g] = mfma_bf16(qrf[1], *(const bf16x8*)(rp + 32), gg[g]);
    }
    float p[4][4];
#pragma unroll
    for (int f = 0; f < 4; ++f) {
#pragma unroll
      for (int e = 0; e < 4; ++e) {
        int r = (lane >> 4) * 4 + e;
        int shift = la + 15 - r;                 // in [0,30]
        int src = (lane & 48) | (shift & 15);
        float d0 = __shfl(gg[f][e], src, 64);
        float d1 = __shfl(gg[f + 1][e], src, 64);
        float bd = (shift & 16) ? d1 : d0;
        float sc = (ac[f][e] + bd) * 0.125f;
        int i_ = iw + r, j_ = j0 + f * 16 + la;
        p[f][e] = (j_ > i_) ? -1e30f : sc;
      }
    }
#pragma unroll
    for (int e = 0; e < 4; ++e) {
      float mx = fmaxf(fmaxf(p[0][e], p[1][e]), fmaxf(p[2][e], p[3][e]));
#pragma unroll
      for (int o = 1; o < 16; o <<= 1) mx = fmaxf(mx, __shfl_xor(mx, o, 64));
      float mnew = fmaxf(m_[e], mx);
      float alpha = __expf(m_[e] - mnew);
      float rs = 0.f;
#pragma unroll
      for (int f = 0; f < 4; ++f) {
        p[f][e] = __expf(p[f][e] - mnew);
        rs += p[f][e];
      }
#pragma unroll
      for (int o = 1; o < 16; o <<= 1) rs += __shfl_xor(rs, o, 64);
      l_[e] = l_[e] * alpha + rs;
      m_[e] = mnew;
#pragma unroll
      for (int d = 0; d < 4; ++d) opv[d][e] *= alpha;
    }
#pragma unroll
    for (int f = 0; f < 4; ++f)
#pragma unroll
      for (int e = 0; e < 4; ++e)
        plds[w][(lane >> 4) * 4 + e][f * 16 + la] = f2bf(p[f][e]);
    bf16x8 pa0 = *(const bf16x8*)&plds[w][la][lk];
    bf16x8 pa1 = *(const bf16x8*)&plds[w][la][32 + lk];
#pragma unroll
    for (int d = 0; d < 4; ++d) {
      const unsigned short* vp = vT + ((long)bn * 64 + d * 16 + la) * S + j0 + lk;
      opv[d] = mfma_bf16(pa0, *(const bf16x8*)vp, opv[d]);
      opv[d] = mfma_bf16(pa1, *(const bf16x8*)(vp + 32), opv[d]);
    }
  }
#pragma unroll
  for (int d = 0; d < 4; ++d) {
#pragma unroll
    for (int e = 0; e < 4; ++e) {
      int i_ = iw + (lane >> 4) * 4 + e;
      int col = nh * 64 + d * 16 + la;
      vec[((long)i_ * Bb + bbv) * 1024 + col] = f2bf(opv[d][e] / l_[e]);
    }
  }
}

// ---------------- residual add + layernorm (in-place on h) ----------------
__global__ __launch_bounds__(256) void add_ln(float* __restrict__ h, const float* __restrict__ x,
                                              const float* __restrict__ g, const float* __restrict__ b) {
  __shared__ float red[8];
  int row = blockIdx.x, t = threadIdx.x;
  long base = (long)row * 1024 + t * 4;
  f32x4 hv = *(const f32x4*)&h[base];
  f32x4 xv = *(const f32x4*)&x[base];
  f32x4 y = hv + xv;
  float s = y[0] + y[1] + y[2] + y[3];
  float q = y[0] * y[0] + y[1] * y[1] + y[2] * y[2] + y[3] * y[3];
#pragma unroll
  for (int o = 1; o < 64; o <<= 1) {
    s += __shfl_xor(s, o, 64);
    q += __shfl_xor(q, o, 64);
  }
  int w = t >> 6, lane = t & 63;
  if (lane == 0) { red[w] = s; red[4 + w] = q; }
  __syncthreads();
  s = red[0] + red[1] + red[2] + red[3];
  q = red[4] + red[5] + red[6] + red[7];
  float mu = s * (1.0f / 1024.0f);
  float var = q * (1.0f / 1024.0f) - mu * mu;
  float rstd = rsqrtf(var + 1e-5f);
  f32x4 gv = *(const f32x4*)&g[t * 4];
  f32x4 bv = *(const f32x4*)&b[t * 4];
  f32x4 o;
#pragma unroll
  for (int e = 0; e < 4; ++e) o[e] = (y[e] - mu) * rstd * gv[e] + bv[e];
  *(f32x4*)&h[base] = o;
}

// ---------------- f32 -> bf16 cvt ----------------
__global__ __launch_bounds__(256) void hcvt(const float* __restrict__ h, unsigned short* __restrict__ o) {
  long i4 = ((long)blockIdx.x * 256 + threadIdx.x) * 4;
  f32x4 v = *(const f32x4*)&h[i4];
  u16x4 r;
#pragma unroll
  for (int e = 0; e < 4; ++e) r[e] = f2bf(v[e]);
  *(u16x4*)&o[i4] = r;
}

// ---------------- gelu (exact) + cvt ----------------
__global__ __launch_bounds__(256) void gelu_cvt(const float* __restrict__ x, unsigned short* __restrict__ o) {
  long i4 = ((long)blockIdx.x * 256 + threadIdx.x) * 4;
  f32x4 v = *(const f32x4*)&x[i4];
  u16x4 r;
#pragma unroll
  for (int e = 0; e < 4; ++e) {
    float t = v[e];
    float gg = 0.5f * t * (1.0f + erff(t * 0.70710678118f));
    r[e] = f2bf(gg);
  }
  *(u16x4*)&o[i4] = r;
}

extern "C" void kernel_launch(void* const* d_in, const int* in_sizes, int n_in,
                              void* d_out, int out_size, void* d_ws, size_t ws_size,
                              hipStream_t stream) {
  const int* tokens = (const int*)d_in[0];
  const float* word_emb = (const float*)d_in[1];
  const float* rwb = (const float*)d_in[2];
  const float* rrb = (const float*)d_in[3];
  const float* qkv_w = (const float*)d_in[4];
  const float* qkv_b = (const float*)d_in[5];
  const float* r_kw = (const float*)d_in[6];
  const float* r_kb = (const float*)d_in[7];
  const float* o_w = (const float*)d_in[8];
  const float* o_b = (const float*)d_in[9];
  const float* ln1g = (const float*)d_in[10];
  const float* ln1b = (const float*)d_in[11];
  const float* ff1w = (const float*)d_in[12];
  const float* ff1b = (const float*)d_in[13];
  const float* ff2w = (const float*)d_in[14];
  const float* ff2b = (const float*)d_in[15];
  const float* ln2g = (const float*)d_in[16];
  const float* ln2b = (const float*)d_in[17];
  const float* fw = (const float*)d_in[18];
  const float* fb = (const float*)d_in[19];

  char* ws = (char*)d_ws;
  unsigned short* WBF = (unsigned short*)(ws + 0);          // 33.6 MB weight bf16 [N,K]
  unsigned short* WRK = (unsigned short*)(ws + 33554432);   // 8.4 MB r_kw^T all layers
  float* H = (float*)(ws + 41943040);                       // 16.8 MB residual stream f32
  unsigned short* ABF = (unsigned short*)(ws + 58720256);   // 33.6 MB bf16 activations
  unsigned short* RBF = (unsigned short*)(ws + 92274688);   // 2 MB r bf16

  char* ob = (char*)d_out;
  float* OUTF = (float*)ob;                                 // 67 MB f32 GEMM out (d_out scratch)
  unsigned short* QW = (unsigned short*)(ob + 67108864);
  unsigned short* QR = (unsigned short*)(ob + 75497472);
  unsigned short* KB = (unsigned short*)(ob + 83886080);
  unsigned short* VT = (unsigned short*)(ob + 92274688);
  unsigned short* RKB = (unsigned short*)(ob + 100663296);
  float* OUT = (float*)d_out;

  embed_k<<<4096, 256, 0, stream>>>(tokens, word_emb, H);
  posr_k<<<4096, 256, 0, stream>>>(RBF);
  // rk for all 4 layers in one GEMM: [S,1024] x [1024, 4096]
  wcvt_t<<<dim3(32, 32, 4), 256, 0, stream>>>(r_kw, WRK, 1024, 1024);
  gemm_bt<<<dim3(32, 8), 256, 0, stream>>>(RBF, WRK, r_kb, OUTF, 1024, 4096, 1024);
  rkb_prep<<<16384, 256, 0, stream>>>(OUTF, RKB);

  for (int l = 0; l < Lll; ++l) {
    hcvt<<<4096, 256, 0, stream>>>(H, ABF);
    wcvt_t<<<dim3(96, 32, 1), 256, 0, stream>>>(qkv_w + (long)l * 1024 * 3072, WBF, 1024, 3072);
    gemm_bt<<<dim3(24, 32), 256, 0, stream>>>(ABF, WBF, qkv_b + l * 3072, OUTF, 4096, 3072, 1024);
    qkv_prep<<<16384, 256, 0, stream>>>(OUTF, rwb, rrb, QW, QR, KB);
    vt_prep<<<dim3(16, 64), 256, 0, stream>>>(OUTF, VT);
    attn_k<<<1024, 256, 0, stream>>>(QW, QR, KB, VT, RKB + (long)l * Hh * S * 64, ABF);
    wcvt_t<<<dim3(32, 32, 1), 256, 0, stream>>>(o_w + (long)l * 1024 * 1024, WBF, 1024, 1024);
    gemm_bt<<<dim3(8, 32), 256, 0, stream>>>(ABF, WBF, o_b + l * 1024, OUTF, 4096, 1024, 1024);
    add_ln<<<4096, 256, 0, stream>>>(H, OUTF, ln1g + l * 1024, ln1b + l * 1024);

    hcvt<<<4096, 256, 0, stream>>>(H, ABF);
    wcvt_t<<<dim3(128, 32, 1), 256, 0, stream>>>(ff1w + (long)l * 1024 * 4096, WBF, 1024, 4096);
    gemm_bt<<<dim3(32, 32), 256, 0, stream>>>(ABF, WBF, ff1b + l * 4096, OUTF, 4096, 4096, 1024);
    gelu_cvt<<<16384, 256, 0, stream>>>(OUTF, ABF);
    wcvt_t<<<dim3(32, 128, 1), 256, 0, stream>>>(ff2w + (long)l * 4096 * 1024, WBF, 4096, 1024);
    gemm_bt<<<dim3(8, 32), 256, 0, stream>>>(ABF, WBF, ff2b + l * 1024, OUTF, 4096, 1024, 4096);
    add_ln<<<4096, 256, 0, stream>>>(H, OUTF, ln2g + l * 1024, ln2b + l * 1024);
  }

  hcvt<<<4096, 256, 0, stream>>>(H, ABF);
  wcvt_t<<<dim3(500, 32, 1), 256, 0, stream>>>(fw, WBF, 1024, 16000);
  gemm_bt<<<dim3(125, 32), 256, 0, stream>>>(ABF, WBF, fb, OUT, 4096, 16000, 1024);
}